// Round 2
// baseline (277.522 us; speedup 1.0000x reference)
//
#include <hip/hip_runtime.h>
#include <hip/hip_bf16.h>
#include <cmath>

constexpr int D_NODE = 5;
constexpr int D_IN   = 10;   // 2 * D_NODE
constexpr int D_HID  = 50;

__global__ __launch_bounds__(256) void edge_mlp_f32(
    const float* __restrict__ x,
    const int* __restrict__ ei,          // harness delivers integer inputs as int32
    const float* __restrict__ W1, const float* __restrict__ b1,
    const float* __restrict__ W2, const float* __restrict__ b2,
    const float* __restrict__ W3, const float* __restrict__ b3,
    float* __restrict__ out, int E)
{
    int e = blockIdx.x * blockDim.x + threadIdx.x;
    if (e >= E) return;

    int s = ei[e];
    int t = ei[E + e];

    float ef[D_IN];
    #pragma unroll
    for (int i = 0; i < D_NODE; ++i) ef[i] = x[(long long)s * D_NODE + i];
    #pragma unroll
    for (int i = 0; i < D_NODE; ++i) ef[D_NODE + i] = x[(long long)t * D_NODE + i];

    // ---- layer 1: 10 -> 50, relu ----
    float h1[D_HID];
    #pragma unroll
    for (int j = 0; j < D_HID; ++j) h1[j] = b1[j];
    #pragma unroll
    for (int i = 0; i < D_IN; ++i) {
        float v = ef[i];
        #pragma unroll
        for (int j = 0; j < D_HID; ++j)
            h1[j] = fmaf(v, W1[i * D_HID + j], h1[j]);
    }
    #pragma unroll
    for (int j = 0; j < D_HID; ++j) h1[j] = fmaxf(h1[j], 0.0f);

    // ---- layer 2: 50 -> 50, relu ----
    float h2[D_HID];
    #pragma unroll
    for (int j = 0; j < D_HID; ++j) h2[j] = b2[j];
    #pragma unroll
    for (int k = 0; k < D_HID; ++k) {
        float v = h1[k];
        #pragma unroll
        for (int j = 0; j < D_HID; ++j)
            h2[j] = fmaf(v, W2[k * D_HID + j], h2[j]);
    }

    // ---- layer 3: 50 -> 1, sigmoid ----
    float o = b3[0];
    #pragma unroll
    for (int k = 0; k < D_HID; ++k)
        o = fmaf(fmaxf(h2[k], 0.0f), W3[k], o);

    out[e] = 1.0f / (1.0f + __expf(-o));
}

extern "C" void kernel_launch(void* const* d_in, const int* in_sizes, int n_in,
                              void* d_out, int out_size, void* d_ws, size_t ws_size,
                              hipStream_t stream) {
    const float* x  = (const float*)d_in[0];
    const int*   ei = (const int*)d_in[1];
    const float* W1 = (const float*)d_in[2];
    const float* b1 = (const float*)d_in[3];
    const float* W2 = (const float*)d_in[4];
    const float* b2 = (const float*)d_in[5];
    const float* W3 = (const float*)d_in[6];
    const float* b3 = (const float*)d_in[7];
    float* out = (float*)d_out;

    int E = in_sizes[1] / 2;   // edge_index is [2, E]
    int block = 256;
    int grid = (E + block - 1) / block;
    edge_mlp_f32<<<grid, block, 0, stream>>>(x, ei, W1, b1, W2, b2, W3, b3, out, E);
}

// Round 3
// 101.443 us; speedup vs baseline: 2.7358x; 2.7358x over previous
//
#include <hip/hip_runtime.h>
#include <hip/hip_bf16.h>

typedef short bf16x8 __attribute__((ext_vector_type(8)));
typedef float f32x4  __attribute__((ext_vector_type(4)));

// round-to-nearest-even f32 -> bf16 bits
__device__ inline ushort f2bf(float f) {
    union { float f; uint u; } v; v.f = f;
    uint r = (v.u + 0x7FFFu + ((v.u >> 16) & 1u)) >> 16;
    return (ushort)r;
}
__device__ inline uint packbf(float a, float b) {
    return (uint)f2bf(a) | ((uint)f2bf(b) << 16);
}

#define LDS_FENCE() asm volatile("s_waitcnt lgkmcnt(0)" ::: "memory")

// Per wave: 32 edges. Block: 4 waves = 128 edges.
// EF LDS tile [32 rows][56 k-pad] bf16, k-layout: 0..4 = x[src], 5 = 0,
//   6..10 = x[tgt], 11..55 = 0.  (112 B row stride, 16B-aligned frag reads)
// H1 LDS tile [16 rows][72 k-pad] bf16 per msub (double-buffered).
__global__ __launch_bounds__(256, 4) void edge_mlp_mfma(
    const float* __restrict__ x,
    const int* __restrict__ ei,
    const float* __restrict__ W1, const float* __restrict__ b1,
    const float* __restrict__ W2, const float* __restrict__ b2,
    const float* __restrict__ W3, const float* __restrict__ b3,
    float* __restrict__ out, int E, int num_tiles)
{
    __shared__ ushort lds_ef[4][32][56];
    __shared__ ushort lds_h1[4][2][16][72];

    const int tid  = threadIdx.x;
    const int w    = tid >> 6;     // wave in block
    const int lane = tid & 63;
    const int c    = lane & 15;    // MFMA col / row-select
    const int g    = lane >> 4;    // MFMA k-group / row-group

    // one-time zero of this wave's EF region (covers all k-pad)
    {
        uint* p = (uint*)&lds_ef[w][0][0];
        #pragma unroll
        for (int i = 0; i < 14; ++i) p[lane + 64 * i] = 0;
    }

    // ---- preload loop-invariant weight B-fragments into registers ----
    // B-frag layout assumption: lane holds col = lane&15, k = 8*(lane>>4)+d
    bf16x8 w1f[4];
    #pragma unroll
    for (int n = 0; n < 4; ++n) {
        #pragma unroll
        for (int d = 0; d < 8; ++d) {
            int ke = 8 * g + d;                       // EF k index
            int r1 = (ke < 5) ? ke : (ke >= 6 && ke < 11) ? ke - 1 : -1;
            int j  = 16 * n + c;
            float v = (r1 >= 0 && j < 50) ? W1[r1 * 50 + j] : 0.f;
            w1f[n][d] = (short)f2bf(v);
        }
    }
    bf16x8 w2f[2][4];
    #pragma unroll
    for (int ks = 0; ks < 2; ++ks) {
        #pragma unroll
        for (int n = 0; n < 4; ++n) {
            #pragma unroll
            for (int d = 0; d < 8; ++d) {
                int k = 32 * ks + 8 * g + d;
                int j = 16 * n + c;
                float v = (k < 50 && j < 50) ? W2[k * 50 + j] : 0.f;
                w2f[ks][n][d] = (short)f2bf(v);
            }
        }
    }
    float b1c[4], b2c[4], w3c[4];
    #pragma unroll
    for (int n = 0; n < 4; ++n) {
        int j = 16 * n + c;
        b1c[n] = (j < 50) ? b1[j] : 0.f;
        b2c[n] = (j < 50) ? b2[j] : 0.f;
        w3c[n] = (j < 50) ? W3[j] : 0.f;
    }
    const float b3s = b3[0];

    for (int bt = blockIdx.x; bt < num_tiles; bt += gridDim.x) {
        const int e0 = bt * 128 + w * 32;

        // ---- gather: 64 lanes each fetch one node row (5 f32), pack bf16 ----
        {
            int el = lane & 31;          // local edge
            int wh = lane >> 5;          // 0 = src, 1 = tgt
            int ge = e0 + el;
            if (ge >= E) ge = 0;         // clamped; stores are guarded
            int idx = ei[(size_t)wh * (size_t)E + (size_t)ge];
            const float* xr = x + (size_t)idx * 5;
            float f0 = xr[0], f1 = xr[1], f2 = xr[2], f3 = xr[3], f4 = xr[4];
            uint* dst = (uint*)&lds_ef[w][el][wh * 6];
            dst[0] = packbf(f0, f1);
            dst[1] = packbf(f2, f3);
            dst[2] = packbf(f4, 0.f);
        }
        LDS_FENCE();

        #pragma unroll
        for (int ms = 0; ms < 2; ++ms) {
            // A-frag: lane holds row = c (edge), k = 8g..8g+7
            bf16x8 aEF = *(const bf16x8*)&lds_ef[w][ms * 16 + c][8 * g];

            // ---- layer 1: h1 = relu(EF @ W1 + b1), bounce via LDS ----
            #pragma unroll
            for (int n = 0; n < 4; ++n) {
                f32x4 z = {0.f, 0.f, 0.f, 0.f};
                f32x4 h = __builtin_amdgcn_mfma_f32_16x16x32_bf16(aEF, w1f[n], z, 0, 0, 0);
                #pragma unroll
                for (int r = 0; r < 4; ++r) {
                    float hv = h[r] + b1c[n];
                    hv = hv > 0.f ? hv : 0.f;
                    // C-layout: row m = 4g+r, col j = 16n+c
                    lds_h1[w][ms][4 * g + r][16 * n + c] = f2bf(hv);
                }
            }
            LDS_FENCE();

            // ---- layer 2: h2 = relu(h1 @ W2 + b2) (K=64, 2 steps) ----
            bf16x8 a0 = *(const bf16x8*)&lds_h1[w][ms][c][8 * g];
            bf16x8 a1 = *(const bf16x8*)&lds_h1[w][ms][c][32 + 8 * g];

            float p0 = 0.f, p1 = 0.f, p2 = 0.f, p3 = 0.f;
            #pragma unroll
            for (int n = 0; n < 4; ++n) {
                f32x4 z = {0.f, 0.f, 0.f, 0.f};
                f32x4 h2 = __builtin_amdgcn_mfma_f32_16x16x32_bf16(a0, w2f[0][n], z, 0, 0, 0);
                h2 = __builtin_amdgcn_mfma_f32_16x16x32_bf16(a1, w2f[1][n], h2, 0, 0, 0);
                // layer 3 partial: sum_j relu(h2[m][j]) * W3[j]
                float t;
                t = h2[0] + b2c[n]; t = t > 0.f ? t : 0.f; p0 = fmaf(t, w3c[n], p0);
                t = h2[1] + b2c[n]; t = t > 0.f ? t : 0.f; p1 = fmaf(t, w3c[n], p1);
                t = h2[2] + b2c[n]; t = t > 0.f ? t : 0.f; p2 = fmaf(t, w3c[n], p2);
                t = h2[3] + b2c[n]; t = t > 0.f ? t : 0.f; p3 = fmaf(t, w3c[n], p3);
            }

            // reduce over the 16 cols (lanes sharing g)
            float pr[4] = {p0, p1, p2, p3};
            #pragma unroll
            for (int r = 0; r < 4; ++r) {
                float v = pr[r];
                v += __shfl_xor(v, 1, 16);
                v += __shfl_xor(v, 2, 16);
                v += __shfl_xor(v, 4, 16);
                v += __shfl_xor(v, 8, 16);
                pr[r] = v;
            }

            if (c == 0) {
                int eo = e0 + ms * 16 + 4 * g;    // rows m = 4g..4g+3
                if (eo + 3 < E) {
                    f32x4 o;
                    #pragma unroll
                    for (int r = 0; r < 4; ++r) {
                        float zz = b3s + pr[r];
                        o[r] = 1.f / (1.f + __expf(-zz));
                    }
                    *(f32x4*)&out[eo] = o;
                }
            }
        }
    }
}

extern "C" void kernel_launch(void* const* d_in, const int* in_sizes, int n_in,
                              void* d_out, int out_size, void* d_ws, size_t ws_size,
                              hipStream_t stream) {
    const float* x  = (const float*)d_in[0];
    const int*   ei = (const int*)d_in[1];
    const float* W1 = (const float*)d_in[2];
    const float* b1 = (const float*)d_in[3];
    const float* W2 = (const float*)d_in[4];
    const float* b2 = (const float*)d_in[5];
    const float* W3 = (const float*)d_in[6];
    const float* b3 = (const float*)d_in[7];
    float* out = (float*)d_out;

    int E = in_sizes[1] / 2;                 // edge_index is [2, E]
    int num_tiles = (E + 127) / 128;
    int grid = num_tiles < 2048 ? num_tiles : 2048;
    edge_mlp_mfma<<<grid, 256, 0, stream>>>(x, ei, W1, b1, W2, b2, W3, b3,
                                            out, E, num_tiles);
}

// Round 4
// 80.893 us; speedup vs baseline: 3.4307x; 1.2540x over previous
//
#include <hip/hip_runtime.h>
#include <hip/hip_bf16.h>

typedef short bf16x8 __attribute__((ext_vector_type(8)));
typedef float f32x4  __attribute__((ext_vector_type(4)));

// RNE f32->bf16 (preload path only)
__device__ inline ushort f2bf(float f) {
    union { float f; uint u; } v; v.f = f;
    uint r = (v.u + 0x7FFFu + ((v.u >> 16) & 1u)) >> 16;
    return (ushort)r;
}
// hot path: pair convert -> v_cvt_pk_bf16_f32
__device__ inline uint packbf(float a, float b) {
    float2 t; t.x = a; t.y = b;
    __hip_bfloat162 h = __float22bfloat162_rn(t);
    union { __hip_bfloat162 h; uint u; } cv; cv.h = h; return cv.u;
}

#define LDS_FENCE() asm volatile("s_waitcnt lgkmcnt(0)" ::: "memory")

// Per wave: 32 edges, 2 subtiles of 16. Block: 4 waves = 128 edges.
// EF LDS tile [32 rows][56 k] bf16; k-layout: 0..4=x[src], 5=0, 6..10=x[tgt], 11..=0.
// All layers in transposed form (h^T = W^T @ x^T); layer-2 consumes layer-1's
// C-fragment directly via a formal-K permutation baked into the W2^T fragments.
__global__ __launch_bounds__(256, 2) void edge_mlp_mfma2(
    const float* __restrict__ x,
    const int* __restrict__ ei,
    const float* __restrict__ W1, const float* __restrict__ b1,
    const float* __restrict__ W2, const float* __restrict__ b2,
    const float* __restrict__ W3, const float* __restrict__ b3,
    float* __restrict__ out, int E, int num_tiles)
{
    __shared__ ushort lds_ef[4][32][56];

    const int tid  = threadIdx.x;
    const int w    = tid >> 6;
    const int lane = tid & 63;
    const int c    = lane & 15;    // edge-in-subtile (output col)
    const int g    = lane >> 4;    // k-group / row-group

    // zero this wave's EF region once (covers all k-pad)
    {
        uint* p = (uint*)&lds_ef[w][0][0];
        #pragma unroll
        for (int i = 0; i < 14; ++i) p[lane + 64 * i] = 0;
    }

    // ---- preload W1^T A-frags: lane holds row hid=16mt+c, k=8g+d (EF k-layout) ----
    bf16x8 w1tf[4];
    #pragma unroll
    for (int mt = 0; mt < 4; ++mt) {
        #pragma unroll
        for (int d = 0; d < 8; ++d) {
            int k  = 8 * g + d;
            int r1 = (k < 5) ? k : (k >= 6 && k < 11) ? k - 1 : -1;
            int j  = 16 * mt + c;                      // hid row of W1^T
            float v = (r1 >= 0 && j < 50) ? W1[r1 * 50 + j] : 0.f;
            w1tf[mt][d] = (short)f2bf(v);
        }
    }
    // ---- preload W2^T A-frags with formal-K permutation:
    //      formal slot (t,g,d) -> actual hid1 = 16*(2t+(d>>2)) + 4g + (d&3) ----
    bf16x8 w2tf[2][4];
    #pragma unroll
    for (int t = 0; t < 2; ++t) {
        #pragma unroll
        for (int mt = 0; mt < 4; ++mt) {
            #pragma unroll
            for (int d = 0; d < 8; ++d) {
                int hid1 = 16 * (2 * t + (d >> 2)) + 4 * g + (d & 3);
                int j    = 16 * mt + c;                // hid2 row of W2^T
                float v = (hid1 < 50 && j < 50) ? W2[hid1 * 50 + j] : 0.f;
                w2tf[t][mt][d] = (short)f2bf(v);
            }
        }
    }
    // per-lane bias / W3 slices, indexed by hid = 16mt+4g+r
    float b1c[4][4], b2c[4][4], w3c[4][4];
    #pragma unroll
    for (int mt = 0; mt < 4; ++mt)
        #pragma unroll
        for (int r = 0; r < 4; ++r) {
            int h = 16 * mt + 4 * g + r;
            b1c[mt][r] = (h < 50) ? b1[h] : 0.f;
            b2c[mt][r] = (h < 50) ? b2[h] : 0.f;
            w3c[mt][r] = (h < 50) ? W3[h] : 0.f;
        }
    const float b3s = b3[0];

    for (int bt = blockIdx.x; bt < num_tiles; bt += gridDim.x) {
        const int e0 = bt * 128 + w * 32;

        // ---- gather: 64 lanes each fetch one node row (5 f32), pack bf16 ----
        {
            int el = lane & 31;
            int wh = lane >> 5;          // 0=src, 1=tgt
            int ge = e0 + el;
            if (ge >= E) ge = 0;
            int idx = ei[(size_t)wh * (size_t)E + (size_t)ge];
            const float* xr = x + (size_t)idx * 5;
            float f0 = xr[0], f1 = xr[1], f2 = xr[2], f3 = xr[3], f4 = xr[4];
            uint* dst = (uint*)&lds_ef[w][el][wh * 6];
            dst[0] = packbf(f0, f1);
            dst[1] = packbf(f2, f3);
            dst[2] = packbf(f4, 0.f);
        }
        LDS_FENCE();

        #pragma unroll
        for (int ms = 0; ms < 2; ++ms) {
            // EF^T B-frag: lane holds col=edge c, k=8g+d
            bf16x8 aEF = *(const bf16x8*)&lds_ef[w][ms * 16 + c][8 * g];

            // ---- layer 1: h1^T = W1^T @ EF^T  (4 m-tiles) ----
            f32x4 hT[4];
            #pragma unroll
            for (int mt = 0; mt < 4; ++mt) {
                f32x4 z = {0.f, 0.f, 0.f, 0.f};
                hT[mt] = __builtin_amdgcn_mfma_f32_16x16x32_bf16(w1tf[mt], aEF, z, 0, 0, 0);
            }

            // ---- bias+relu+pack: C-frag (rows hid=16mt+4g+r, col edge=c)
            //      becomes layer-2 B-frags directly (formal-K permutation) ----
            uint pk[4][2];
            #pragma unroll
            for (int mt = 0; mt < 4; ++mt) {
                float v0 = fmaxf(hT[mt][0] + b1c[mt][0], 0.f);
                float v1 = fmaxf(hT[mt][1] + b1c[mt][1], 0.f);
                float v2 = fmaxf(hT[mt][2] + b1c[mt][2], 0.f);
                float v3 = fmaxf(hT[mt][3] + b1c[mt][3], 0.f);
                pk[mt][0] = packbf(v0, v1);
                pk[mt][1] = packbf(v2, v3);
            }
            union { uint u[4]; bf16x8 v; } uu;
            uu.u[0] = pk[0][0]; uu.u[1] = pk[0][1];
            uu.u[2] = pk[1][0]; uu.u[3] = pk[1][1];
            bf16x8 bB0 = uu.v;
            uu.u[0] = pk[2][0]; uu.u[1] = pk[2][1];
            uu.u[2] = pk[3][0]; uu.u[3] = pk[3][1];
            bf16x8 bB1 = uu.v;

            // ---- layer 2: h2^T = W2^T @ h1^T (4 m-tiles x K=64) ----
            f32x4 h2T[4];
            #pragma unroll
            for (int mt = 0; mt < 4; ++mt) {
                f32x4 z = {0.f, 0.f, 0.f, 0.f};
                h2T[mt] = __builtin_amdgcn_mfma_f32_16x16x32_bf16(w2tf[0][mt], bB0, z, 0, 0, 0);
                h2T[mt] = __builtin_amdgcn_mfma_f32_16x16x32_bf16(w2tf[1][mt], bB1, h2T[mt], 0, 0, 0);
            }

            // ---- layer 3: per-lane partial dot over its 16 hid rows ----
            float p = 0.f;
            #pragma unroll
            for (int mt = 0; mt < 4; ++mt) {
                #pragma unroll
                for (int r = 0; r < 4; ++r) {
                    float t = fmaxf(h2T[mt][r] + b2c[mt][r], 0.f);
                    p = fmaf(t, w3c[mt][r], p);
                }
            }
            // reduce across the 4 g-groups (hid partition)
            p += __shfl_xor(p, 16);
            p += __shfl_xor(p, 32);

            if (g == 0) {
                int eo = e0 + ms * 16 + c;
                if (eo < E) {
                    float zz = p + b3s;
                    out[eo] = 1.f / (1.f + __expf(-zz));
                }
            }
        }
    }
}

extern "C" void kernel_launch(void* const* d_in, const int* in_sizes, int n_in,
                              void* d_out, int out_size, void* d_ws, size_t ws_size,
                              hipStream_t stream) {
    const float* x  = (const float*)d_in[0];
    const int*   ei = (const int*)d_in[1];
    const float* W1 = (const float*)d_in[2];
    const float* b1 = (const float*)d_in[3];
    const float* W2 = (const float*)d_in[4];
    const float* b2 = (const float*)d_in[5];
    const float* W3 = (const float*)d_in[6];
    const float* b3 = (const float*)d_in[7];
    float* out = (float*)d_out;

    int E = in_sizes[1] / 2;                 // edge_index is [2, E]
    int num_tiles = (E + 127) / 128;
    int grid = num_tiles < 2048 ? num_tiles : 2048;
    edge_mlp_mfma2<<<grid, 256, 0, stream>>>(x, ei, W1, b1, W2, b2, W3, b3,
                                             out, E, num_tiles);
}